// Round 2
// baseline (200.856 us; speedup 1.0000x reference)
//
#include <hip/hip_runtime.h>
#include <hip/hip_bf16.h>

// ---- problem constants ----
#define BATCH 2
#define SEQ   2048
#define EMB   1024
#define NHEAD 16
#define HDIM  64
#define MTOT  (BATCH*SEQ)     // 4096
#define KTOT  EMB             // 1024

#define NX  (MTOT*EMB)        // 4,194,304  X elems
#define NW1 (3*EMB*EMB)       // 3,145,728  Wqkv elems
#define NW2 (EMB*EMB)         // 1,048,576  Wout elems
#define NCVT (NX+NW1+NW2)

typedef short bf8 __attribute__((ext_vector_type(8)));   // 8 bf16 (4 VGPRs) MFMA A/B frag
typedef short s4v __attribute__((ext_vector_type(4)));   // 4 bf16, 8B
typedef float f4  __attribute__((ext_vector_type(4)));   // MFMA C/D frag
typedef unsigned int uint;

__device__ __forceinline__ short f2b(float f) {
    __hip_bfloat16 h = __float2bfloat16(f);
    return __builtin_bit_cast(short, h);
}
// async global->LDS, 16B per lane; lds dest = wave-uniform base + lane*16
__device__ __forceinline__ void gl_lds16(const short* g, short* l) {
    __builtin_amdgcn_global_load_lds(
        (const __attribute__((address_space(1))) uint*)g,
        (__attribute__((address_space(3))) uint*)l, 16, 0, 0);
}
// 64B-row LDS tiles: bank swizzle (store global chunk c^f(r) at LDS chunk c).
// Invariant: valid when staging row-base and fragment row-base are both %16==0.
#define SWZ_SRC(lane)      ((((lane) ^ ((lane)>>2) ^ ((lane)>>4)) & 3) * 8)
#define SWZ_RD(quad, l16)  ((((quad) ^ (l16) ^ ((l16)>>2)) & 3) * 8)

#define BARRIER() do { asm volatile("" ::: "memory"); \
                       __builtin_amdgcn_s_barrier(); \
                       asm volatile("" ::: "memory"); } while (0)

// ============================================================================
// Kernel 0: fp32 -> bf16 convert (X, Wqkv, Wout). Coalesced float4 -> bf16x4.
// ============================================================================
__global__ __launch_bounds__(256) void cvt_all(
    const float* __restrict__ X, const float* __restrict__ W1,
    const float* __restrict__ W2,
    short* __restrict__ xb, short* __restrict__ w1b, short* __restrict__ w2b)
{
    int i4 = (blockIdx.x * 256 + threadIdx.x) * 4;
    const float* src; short* dst; int off;
    if (i4 < NX)            { src = X;  dst = xb;  off = i4; }
    else if (i4 < NX + NW1) { src = W1; dst = w1b; off = i4 - NX; }
    else                    { src = W2; dst = w2b; off = i4 - NX - NW1; }
    float4 v = *(const float4*)&src[off];
    s4v o; o[0]=f2b(v.x); o[1]=f2b(v.y); o[2]=f2b(v.z); o[3]=f2b(v.w);
    *(s4v*)&dst[off] = o;
}

// ============================================================================
// Kernel 1: QKV projection — R14: 256x256 tile, BK=64, 8 waves (2Mx4N),
// m201-style 4-phase/K-tile schedule with COUNTED vmcnt (T3+T4) + setprio (T5).
// Per phase: {ds_read subtile | 2 global_load_lds | [vmcnt(4)] | barrier |
//             16 MFMA (setprio-wrapped) | barrier}. vmcnt(4) at phases 0,1,3
// only — never drains to 0 in the main loop (4-8 loads always in flight).
// Release algebra (verified): per wave, staged regions == regions it reads
// (A-half wh by waves {4wh..4wh+3}; B-slice wl by waves {wl, wl+4}), stage
// order {Am0,Bn0,Bn1,Am1} with reads lagging 3-4 phases, so per-wave vmcnt +
// block barrier => global visibility. Last iter prefetches into the dead
// buffer (sources stay inside d_ws) to keep vmcnt counts uniform.
// Grid 16x12 = 192 blocks; XCD-chunked 4bm x 6bn (5 MB/XCD working set).
// LDS 128KB (A 2x32KB, B 2x32KB). Proven XOR chunk swizzle; scatter epilogue.
// ============================================================================
__global__ __launch_bounds__(512, 1) void gemm_qkv(
    const short* __restrict__ Xb, const short* __restrict__ Wb,
    const float* __restrict__ bias,
    short* __restrict__ qb, short* __restrict__ kb, short* __restrict__ vtb)
{
    __shared__ __align__(16) short As[2*2*256*32];   // 64KB [buf][kc][row][32sh]
    __shared__ __align__(16) short Bs[2*2*256*32];   // 64KB [buf][kc][row][32sh]
    const int tid  = threadIdx.x;
    const int lane = tid & 63;
    const int w    = tid >> 6;                       // 0..7
    const int l16  = lane & 15, quad = lane >> 4;
    const int wh   = w >> 2;                         // A-half (0/1), m-rows wh*128
    const int wl   = w & 3;                          // B-slice, n-cols wl*64
    const int wm   = wh * 128;
    const int wn   = wl * 64;
    const int srow = lane >> 2;
    const int scol = SWZ_SRC(lane);

    // XCD-chunked bijective swizzle: 192 blocks, 24/XCD as 4bm x 6bn
    const int id  = blockIdx.x;
    const int x   = id & 7;                          // XCD
    const int j   = id >> 3;                         // 0..23
    const int bmL = j / 6, bnL = j - bmL*6;
    const int bm  = (x & 3)*4 + bmL;                 // 0..15
    const int bn  = (x >> 2)*6 + bnL;                // 0..11
    const int row0 = bm * 256, col0 = bn * 256;

    // staging sources/dests: wave stages exactly what it reads.
    // A: half wh, sub-halves m0 (rows +0..63) / m1 (+64..127), 16 rows each inst
    // B: slice wl, sub-halves n0 (+0..31) / n1 (+32..63), wh picks 16-row half
    const short* pA0[2]; const short* pA1[2];
    const short* pB0[2]; const short* pB1[2];
    int dA0[2], dA1[2], dB0[2], dB1[2];
    #pragma unroll
    for (int kc = 0; kc < 2; kc++) {
        int ra0 = wm + 0  + wl*16;
        int ra1 = wm + 64 + wl*16;
        int rb0 = wn + 0  + wh*16;
        int rb1 = wn + 32 + wh*16;
        pA0[kc] = &Xb[(size_t)(row0 + ra0 + srow)*KTOT + kc*32 + scol];
        pA1[kc] = &Xb[(size_t)(row0 + ra1 + srow)*KTOT + kc*32 + scol];
        pB0[kc] = &Wb[(size_t)(col0 + rb0 + srow)*KTOT + kc*32 + scol];
        pB1[kc] = &Wb[(size_t)(col0 + rb1 + srow)*KTOT + kc*32 + scol];
        dA0[kc] = kc*8192 + ra0*32;
        dA1[kc] = kc*8192 + ra1*32;
        dB0[kc] = kc*8192 + rb0*32;
        dB1[kc] = kc*8192 + rb1*32;
    }

    f4 acc[8][4] = {};

    // prologue: stage tile 0 -> buf0, order {Am0, Bn0, Bn1, Am1}
    gl_lds16(pA0[0], &As[dA0[0]]); gl_lds16(pA0[1], &As[dA0[1]]);
    gl_lds16(pB0[0], &Bs[dB0[0]]); gl_lds16(pB0[1], &Bs[dB0[1]]);
    gl_lds16(pB1[0], &Bs[dB1[0]]); gl_lds16(pB1[1], &Bs[dB1[1]]);
    gl_lds16(pA1[0], &As[dA1[0]]); gl_lds16(pA1[1], &As[dA1[1]]);
    asm volatile("s_waitcnt vmcnt(4)" ::: "memory");   // Am0,Bn0 of tile0 done
    BARRIER();

    const int swz = SWZ_RD(quad, l16);
    bf8 af[4][2], bf0[2][2], bf1[2][2];

    for (int t = 0; t < 16; t++) {
        const int ab = (t & 1) * 16384;              // compute buf
        const int nb = ((t & 1) ^ 1) * 16384;        // stage buf
        const int ko = (t + 1) * 64;                 // next K-tile offset

        // ---- phase 0: read Am0 + Bn0; stage Am0(t+1); MFMA m0 x n0 ----
        #pragma unroll
        for (int kc = 0; kc < 2; kc++) {
            #pragma unroll
            for (int m = 0; m < 4; m++)
                af[m][kc] = *(const bf8*)&As[ab + kc*8192 + (wm + m*16 + l16)*32 + swz];
            #pragma unroll
            for (int n = 0; n < 2; n++)
                bf0[n][kc] = *(const bf8*)&Bs[ab + kc*8192 + (wn + n*16 + l16)*32 + swz];
        }
        gl_lds16(pA0[0] + ko, &As[nb + dA0[0]]);
        gl_lds16(pA0[1] + ko, &As[nb + dA0[1]]);
        asm volatile("s_waitcnt vmcnt(4)" ::: "memory");   // release Bn1(t)
        BARRIER();
        __builtin_amdgcn_s_setprio(1);
        #pragma unroll
        for (int m = 0; m < 4; m++)
            #pragma unroll
            for (int n = 0; n < 2; n++)
                #pragma unroll
                for (int kc = 0; kc < 2; kc++)
                    acc[m][n] = __builtin_amdgcn_mfma_f32_16x16x32_bf16(af[m][kc], bf0[n][kc], acc[m][n], 0, 0, 0);
        __builtin_amdgcn_s_setprio(0);
        BARRIER();

        // ---- phase 1: read Bn1; stage Bn0(t+1); MFMA m0 x n1 ----
        #pragma unroll
        for (int kc = 0; kc < 2; kc++)
            #pragma unroll
            for (int n = 0; n < 2; n++)
                bf1[n][kc] = *(const bf8*)&Bs[ab + kc*8192 + (wn + 32 + n*16 + l16)*32 + swz];
        gl_lds16(pB0[0] + ko, &Bs[nb + dB0[0]]);
        gl_lds16(pB0[1] + ko, &Bs[nb + dB0[1]]);
        asm volatile("s_waitcnt vmcnt(4)" ::: "memory");   // release Am1(t)
        BARRIER();
        __builtin_amdgcn_s_setprio(1);
        #pragma unroll
        for (int m = 0; m < 4; m++)
            #pragma unroll
            for (int n = 0; n < 2; n++)
                #pragma unroll
                for (int kc = 0; kc < 2; kc++)
                    acc[m][2+n] = __builtin_amdgcn_mfma_f32_16x16x32_bf16(af[m][kc], bf1[n][kc], acc[m][2+n], 0, 0, 0);
        __builtin_amdgcn_s_setprio(0);
        BARRIER();

        // ---- phase 2: read Am1 (reuse af); stage Bn1(t+1); MFMA m1 x n1 ----
        #pragma unroll
        for (int kc = 0; kc < 2; kc++)
            #pragma unroll
            for (int m = 0; m < 4; m++)
                af[m][kc] = *(const bf8*)&As[ab + kc*8192 + (wm + 64 + m*16 + l16)*32 + swz];
        gl_lds16(pB1[0] + ko, &Bs[nb + dB1[0]]);
        gl_lds16(pB1[1] + ko, &Bs[nb + dB1[1]]);
        BARRIER();                                         // no vmcnt check here
        __builtin_amdgcn_s_setprio(1);
        #pragma unroll
        for (int m = 0; m < 4; m++)
            #pragma unroll
            for (int n = 0; n < 2; n++)
                #pragma unroll
                for (int kc = 0; kc < 2; kc++)
                    acc[4+m][2+n] = __builtin_amdgcn_mfma_f32_16x16x32_bf16(af[m][kc], bf1[n][kc], acc[4+m][2+n], 0, 0, 0);
        __builtin_amdgcn_s_setprio(0);
        BARRIER();

        // ---- phase 3: no reads; stage Am1(t+1); MFMA m1 x n0 ----
        gl_lds16(pA1[0] + ko, &As[nb + dA1[0]]);
        gl_lds16(pA1[1] + ko, &As[nb + dA1[1]]);
        asm volatile("s_waitcnt vmcnt(4)" ::: "memory");   // release Am0,Bn0(t+1)
        BARRIER();
        __builtin_amdgcn_s_setprio(1);
        #pragma unroll
        for (int m = 0; m < 4; m++)
            #pragma unroll
            for (int n = 0; n < 2; n++)
                #pragma unroll
                for (int kc = 0; kc < 2; kc++)
                    acc[4+m][n] = __builtin_amdgcn_mfma_f32_16x16x32_bf16(af[m][kc], bf0[n][kc], acc[4+m][n], 0, 0, 0);
        __builtin_amdgcn_s_setprio(0);
        BARRIER();
    }

    #pragma unroll
    for (int m = 0; m < 8; m++)
    #pragma unroll
    for (int n = 0; n < 4; n++) {
        int colg = col0 + wn + n*16 + l16;
        float bv = bias[colg];
        #pragma unroll
        for (int r = 0; r < 4; r++) {
            int rowg = row0 + wm + m*16 + quad*4 + r;
            short h = f2b(acc[m][n][r] + bv);
            int bb2 = rowg >> 11, s = rowg & 2047;
            if (colg < 1024) {
                int hh = colg >> 6, d = colg & 63;
                qb[(((bb2*NHEAD + hh)*SEQ + s) << 6) + d] = h;
            } else if (colg < 2048) {
                int c2 = colg - 1024, hh = c2 >> 6, d = c2 & 63;
                kb[(((bb2*NHEAD + hh)*SEQ + s) << 6) + d] = h;
            } else {
                int c3 = colg - 2048, hh = c3 >> 6, d = c3 & 63;
                int ssw = (s & ~63) | (((s & 15) << 2) | ((s >> 4) & 3));
                vtb[((bb2*NHEAD + hh)*HDIM + d)*SEQ + ssw] = h;
            }
        }
    }
}

// ============================================================================
// Kernel 2: causal flash attention (unchanged from R10). Balanced map: CU
// slot gets 4 tiles of the SAME head, tq in {j,15-j,16+j,31-j}. LDS K/V dbuf
// DMA; masked stage peeled; no-max softmax; exp2; v_perm pack.
// ============================================================================
__global__ __launch_bounds__(256, 4) void attn(
    const short* __restrict__ qb, const short* __restrict__ kb,
    const short* __restrict__ vtb, short* __restrict__ ctx)
{
    __shared__ __align__(16) short Ks[2*4096];      // 16KB [buf][c][key][32sh]
    __shared__ __align__(16) short Vs[2*4096];      // 16KB
    __shared__ __align__(16) short pl[4][16*64];    //  8KB
    const int tid = threadIdx.x;
    const int w = tid >> 6, lane = tid & 63;
    const int l16 = lane & 15, quad = lane >> 4;
    const int f  = blockIdx.x;                      // 0..1023
    const int bh = f & 31;
    const int j5 = (f >> 5) & 7;
    const int hq = f >> 8;                          // 0..3
    const int tq = (hq == 0) ? j5 : (hq == 1) ? (15 - j5)
                 : (hq == 2) ? (16 + j5) : (31 - j5);
    const int q0w = tq*64 + w*16;
    const int base = bh * (SEQ*HDIM);
    short* myp = pl[w];
    const float SC = 0.125f * 1.44269504f;          // 1/sqrt(64) * log2(e)

    const int lq  = lane >> 2;
    const int lsw = SWZ_SRC(lane);

    const bool isk = (w < 2);
    short* tb = isk ? Ks : Vs;
    const int sstep = isk ? 64*HDIM : 64;
    const short* sp0; const short* sp1; const short* sp2; const short* sp3;
    int dof[4];
    {
        const int wb2 = (w & 1) * 4;
        #pragma unroll
        for (int tt = 0; tt < 4; tt++) {
            int t = wb2 + tt, cc = t & 1, g = (t >> 1) & 3;
            dof[tt] = (cc*64 + g*16)*32;
            const short* s = isk ? &kb[base + (g*16 + lq)*HDIM + cc*32 + lsw]
                                 : &vtb[base + (g*16 + lq)*SEQ + cc*32 + lsw];
            if (tt == 0) sp0 = s; else if (tt == 1) sp1 = s;
            else if (tt == 2) sp2 = s; else sp3 = s;
        }
    }

    bf8 qa[2];
    #pragma unroll
    for (int kc = 0; kc < 2; kc++)
        qa[kc] = *(const bf8*)&qb[base + (q0w + l16)*HDIM + kc*32 + quad*8];

    f4 o[4] = {};
    float lacc[4] = {};
    const int rdK = l16*32 + SWZ_RD(quad, l16);

    gl_lds16(sp0, tb + dof[0]); gl_lds16(sp1, tb + dof[1]);
    gl_lds16(sp2, tb + dof[2]); gl_lds16(sp3, tb + dof[3]);
    sp0 += sstep; sp1 += sstep; sp2 += sstep; sp3 += sstep;
    __syncthreads();

    int buf = 0;
    for (int st = 0; st <= tq; st++) {
        if (st < tq) {
            short* d = tb + (buf ^ 1)*4096;
            gl_lds16(sp0, d + dof[0]); gl_lds16(sp1, d + dof[1]);
            gl_lds16(sp2, d + dof[2]); gl_lds16(sp3, d + dof[3]);
            sp0 += sstep; sp1 += sstep; sp2 += sstep; sp3 += sstep;
        }
        const int kbase = buf*4096 + rdK;
        f4 s[4] = {};
        #pragma unroll
        for (int kf = 0; kf < 4; kf++)
            #pragma unroll
            for (int c = 0; c < 2; c++) {
                bf8 kfr = *(const bf8*)&Ks[kbase + (c*64 + kf*16)*32];
                s[kf] = __builtin_amdgcn_mfma_f32_16x16x32_bf16(qa[c], kfr, s[kf], 0, 0, 0);
            }
        if (st == tq) {
            const int j0 = st*64;
            #pragma unroll
            for (int r = 0; r < 4; r++) {
                const int row = quad*4 + r;
                const int qi  = q0w + row;
                float e[4];
                #pragma unroll
                for (int kf = 0; kf < 4; kf++) {
                    e[kf] = __builtin_amdgcn_exp2f(s[kf][r] * SC);
                    if (j0 + kf*16 + l16 > qi) e[kf] = 0.0f;
                    lacc[r] += e[kf];
                }
                uint u01 = __builtin_amdgcn_perm(__builtin_bit_cast(uint, e[1]),
                                                 __builtin_bit_cast(uint, e[0]), 0x07060302u);
                uint u23 = __builtin_amdgcn_perm(__builtin_bit_cast(uint, e[3]),
                                                 __builtin_bit_cast(uint, e[2]), 0x07060302u);
                uint2 pk = {u01, u23};
                int c8 = ((l16 >> 1) ^ (row & 7));
                *(uint2*)&myp[row*64 + c8*8 + (l16 & 1)*4] = pk;
            }
        } else {
            #pragma unroll
            for (int r = 0; r < 4; r++) {
                const int row = quad*4 + r;
                float e[4];
                #pragma unroll
                for (int kf = 0; kf < 4; kf++) {
                    e[kf] = __builtin_amdgcn_exp2f(s[kf][r] * SC);
                    lacc[r] += e[kf];
                }
                uint u01 = __builtin_amdgcn_perm(__builtin_bit_cast(uint, e[1]),
                                                 __builtin_bit_cast(uint, e[0]), 0x07060302u);
                uint u23 = __builtin_amdgcn_perm(__builtin_bit_cast(uint, e[3]),
                                                 __builtin_bit_cast(uint, e[2]), 0x07060302u);
                uint2 pk = {u01, u23};
                int c8 = ((l16 >> 1) ^ (row & 7));
                *(uint2*)&myp[row*64 + c8*8 + (l16 & 1)*4] = pk;
            }
        }
        asm volatile("" ::: "memory");
        bf8 pa[2];
        #pragma unroll
        for (int kc = 0; kc < 2; kc++)
            pa[kc] = *(const bf8*)&myp[l16*64 + (((kc*4 + quad) ^ (l16 & 7)))*8];
        #pragma unroll
        for (int dt = 0; dt < 4; dt++)
            #pragma unroll
            for (int c = 0; c < 2; c++) {
                bf8 vf = *(const bf8*)&Vs[kbase + (c*64 + dt*16)*32];
                o[dt] = __builtin_amdgcn_mfma_f32_16x16x32_bf16(pa[c], vf, o[dt], 0, 0, 0);
            }
        __syncthreads();
        buf ^= 1;
    }
    #pragma unroll
    for (int r = 0; r < 4; r++) {
        float v = lacc[r];
        v += __shfl_xor(v, 1);
        v += __shfl_xor(v, 2);
        v += __shfl_xor(v, 4);
        v += __shfl_xor(v, 8);
        lacc[r] = v;
    }
    const int b = bh >> 4, h = bh & 15;
    #pragma unroll
    for (int r = 0; r < 4; r++) {
        float inv = 1.0f / lacc[r];
        int qi = q0w + quad*4 + r;
        int rowoff = (b*SEQ + qi)*EMB + h*HDIM;
        #pragma unroll
        for (int dt = 0; dt < 4; dt++)
            ctx[rowoff + dt*16 + l16] = f2b(o[dt][r] * inv);
    }
}

// ============================================================================
// Kernel 3: output projection (reverted to R12/R0-proven form). 64x64 tile,
// BK=64, 1024 blocks = 4 blocks/CU TLP. Bias in epilogue, plain stores.
// ============================================================================
__global__ __launch_bounds__(256) void gemm_out(
    const short* __restrict__ A, const short* __restrict__ Wb,
    const float* __restrict__ bias, float* __restrict__ out)
{
    __shared__ __align__(16) short As[2*64*32];   // 8KB [kc][row][32sh]
    __shared__ __align__(16) short Bs[2*64*32];   // 8KB
    const int f = blockIdx.x;                   // 0..1023
    const int xcd = f & 7, i = f >> 3;          // i: 0..127
    const int by = xcd*2 + (i & 1);             // 0..15
    const int bx = i >> 1;                      // 0..63
    const int tid  = threadIdx.x;
    const int lane = tid & 63;
    const int w    = tid >> 6;
    const int l16  = lane & 15, quad = lane >> 4;
    const int wm   = (w >> 1) * 32, wn = (w & 1) * 32;
    const int srow = (lane >> 2);
    const int scol = SWZ_SRC(lane);
    f4 acc[2][2] = {};
    for (int k0 = 0; k0 < KTOT; k0 += 64) {
        #pragma unroll
        for (int kc = 0; kc < 2; kc++) {
            int ra = bx*64 + w*16 + srow;
            gl_lds16(&A[(size_t)ra*KTOT + k0 + kc*32 + scol],  &As[kc*2048 + (w*16)*32]);
            int rb = by*64 + w*16 + srow;
            gl_lds16(&Wb[(size_t)rb*KTOT + k0 + kc*32 + scol], &Bs[kc*2048 + (w*16)*32]);
        }
        __syncthreads();
        #pragma unroll
        for (int kc = 0; kc < 2; kc++) {
            bf8 af[2], bf[2];
            #pragma unroll
            for (int t = 0; t < 2; t++) {
                af[t] = *(const bf8*)&As[kc*2048 + (wm + t*16 + l16)*32 + SWZ_RD(quad, l16)];
                bf[t] = *(const bf8*)&Bs[kc*2048 + (wn + t*16 + l16)*32 + SWZ_RD(quad, l16)];
            }
            #pragma unroll
            for (int mt = 0; mt < 2; mt++)
                #pragma unroll
                for (int nt = 0; nt < 2; nt++)
                    acc[mt][nt] = __builtin_amdgcn_mfma_f32_16x16x32_bf16(af[mt], bf[nt], acc[mt][nt], 0, 0, 0);
        }
        __syncthreads();
    }
    #pragma unroll
    for (int mt = 0; mt < 2; mt++)
    #pragma unroll
    for (int nt = 0; nt < 2; nt++) {
        int colg = by*64 + wn + nt*16 + l16;
        float bv = bias[colg];
        #pragma unroll
        for (int r = 0; r < 4; r++) {
            int rowg = bx*64 + wm + mt*16 + quad*4 + r;
            out[(size_t)rowg*EMB + colg] = acc[mt][nt][r] + bv;
        }
    }
}

extern "C" void kernel_launch(void* const* d_in, const int* in_sizes, int n_in,
                              void* d_out, int out_size, void* d_ws, size_t ws_size,
                              hipStream_t stream) {
    const float* X    = (const float*)d_in[0];   // [B,S,E] fp32
    const float* Wqkv = (const float*)d_in[1];   // [3E,E]  fp32
    const float* Bqkv = (const float*)d_in[2];   // [3E]    fp32
    const float* Wout = (const float*)d_in[3];   // [E,E]   fp32
    const float* Bout = (const float*)d_in[4];   // [E]     fp32
    float* out = (float*)d_out;                  // [B,S,E] fp32

    short* xb    = (short*)d_ws;                 // bf16 X      (8 MB)
    short* w1b   = xb  + NX;                     // bf16 Wqkv   (6 MB)
    short* w2b   = w1b + NW1;                    // bf16 Wout   (2 MB)
    short* qb    = w2b + NW2;
    short* kb    = qb  + NX;
    short* vtb   = kb  + NX;
    short* ctx   = vtb + NX;                     // total 48 MB

    cvt_all<<<NCVT/1024, 256, 0, stream>>>(X, Wqkv, Wout, xb, w1b, w2b);
    gemm_qkv<<<dim3(192), 512, 0, stream>>>(xb, w1b, Bqkv, qb, kb, vtb);
    attn<<<dim3(1024), 256, 0, stream>>>(qb, kb, vtb, ctx);
    gemm_out<<<dim3(1024), 256, 0, stream>>>(ctx, w2b, Bout, out);
}

// Round 3
// 180.170 us; speedup vs baseline: 1.1148x; 1.1148x over previous
//
#include <hip/hip_runtime.h>
#include <hip/hip_bf16.h>

// ---- problem constants ----
#define BATCH 2
#define SEQ   2048
#define EMB   1024
#define NHEAD 16
#define HDIM  64
#define MTOT  (BATCH*SEQ)     // 4096
#define KTOT  EMB             // 1024

#define NX  (MTOT*EMB)        // 4,194,304  X elems
#define NW1 (3*EMB*EMB)       // 3,145,728  Wqkv elems
#define NW2 (EMB*EMB)         // 1,048,576  Wout elems
#define NCVT (NX+NW1+NW2)

typedef short bf8 __attribute__((ext_vector_type(8)));   // 8 bf16 (4 VGPRs) MFMA A/B frag
typedef short s4v __attribute__((ext_vector_type(4)));   // 4 bf16, 8B
typedef float f4  __attribute__((ext_vector_type(4)));   // MFMA C/D frag
typedef unsigned int uint;

__device__ __forceinline__ short f2b(float f) {
    __hip_bfloat16 h = __float2bfloat16(f);
    return __builtin_bit_cast(short, h);
}
// async global->LDS, 16B per lane; lds dest = wave-uniform base + lane*16
__device__ __forceinline__ void gl_lds16(const short* g, short* l) {
    __builtin_amdgcn_global_load_lds(
        (const __attribute__((address_space(1))) uint*)g,
        (__attribute__((address_space(3))) uint*)l, 16, 0, 0);
}
// 64B-row LDS tiles: bank swizzle (store global chunk c^f(r) at LDS chunk c).
#define SWZ_SRC(lane)      ((((lane) ^ ((lane)>>2) ^ ((lane)>>4)) & 3) * 8)
#define SWZ_RD(quad, l16)  ((((quad) ^ (l16) ^ ((l16)>>2)) & 3) * 8)

// ============================================================================
// Kernel 0: fp32 -> bf16 convert (X, Wqkv, Wout). Coalesced float4 -> bf16x4.
// ============================================================================
__global__ __launch_bounds__(256) void cvt_all(
    const float* __restrict__ X, const float* __restrict__ W1,
    const float* __restrict__ W2,
    short* __restrict__ xb, short* __restrict__ w1b, short* __restrict__ w2b)
{
    int i4 = (blockIdx.x * 256 + threadIdx.x) * 4;
    const float* src; short* dst; int off;
    if (i4 < NX)            { src = X;  dst = xb;  off = i4; }
    else if (i4 < NX + NW1) { src = W1; dst = w1b; off = i4 - NX; }
    else                    { src = W2; dst = w2b; off = i4 - NX - NW1; }
    float4 v = *(const float4*)&src[off];
    s4v o; o[0]=f2b(v.x); o[1]=f2b(v.y); o[2]=f2b(v.z); o[3]=f2b(v.w);
    *(s4v*)&dst[off] = o;
}

// ============================================================================
// Kernel 1: QKV projection — R15: R10-exact proven structure (128x128 tile,
// BK=64, single-buffer DMA staging, 768 blocks ~3/CU TLP) + NEW: XCD-chunked
// 2-D region swizzle (T1). 64 regions of 4(M)x3(N) tiles, 8 regions/XCD:
// per-XCD working set A 4x256KB + B 3x256KB = 1.75MB fits 4MB L2 (reuse
// x4/x3). Mechanism: R0's FETCH 28.8MB vs 14MB ideal => the per-iter vmcnt(0)
// drain waits on ~900cy HBM misses; L2-localizing the panels shortens the
// serial drain. (R13 2ph-dbuf and R14 4-phase both REVERTED: -2.5/-31 µs.)
// ============================================================================
__global__ __launch_bounds__(256) void gemm_qkv(
    const short* __restrict__ Xb, const short* __restrict__ Wb,
    const float* __restrict__ bias,
    short* __restrict__ qb, short* __restrict__ kb, short* __restrict__ vtb)
{
    __shared__ __align__(16) short As[2*128*32];   // 16KB [kc][row][32sh]
    __shared__ __align__(16) short Bs[2*128*32];   // 16KB
    const int tid  = threadIdx.x;
    const int lane = tid & 63;
    const int w    = tid >> 6;
    const int l16  = lane & 15, quad = lane >> 4;
    const int wm   = (w >> 1) * 64, wn = (w & 1) * 64;
    const int srow = (lane >> 2);
    const int scol = SWZ_SRC(lane);

    // XCD-chunked region swizzle: id -> (xcd, region, pos) -> (bm, bn).
    // Bijective over 768: R = rg*8+xcd in [0,64); bm=(R&7)*4+(p&3) in [0,32);
    // bn=(R>>3)*3+(p>>2) in [0,24).
    const int id  = blockIdx.x;
    const int xcd = id & 7, k = id >> 3;            // k: 0..95
    const int rg  = k / 12, p = k - rg*12;          // rg: 0..7, p: 0..11
    const int R   = rg*8 + xcd;                     // 0..63
    const int bm  = (R & 7)*4 + (p & 3);            // 0..31  (M tile)
    const int bn  = (R >> 3)*3 + (p >> 2);          // 0..23  (N tile)

    f4 acc[4][4] = {};
    for (int k0 = 0; k0 < KTOT; k0 += 64) {
        #pragma unroll
        for (int t = 0; t < 4; t++) {
            const int rr = w*32 + (t & 1)*16;
            const int kc = t >> 1;
            int ra = bm*128 + rr + srow;
            gl_lds16(&Xb[(size_t)ra*KTOT + k0 + kc*32 + scol], &As[kc*4096 + rr*32]);
            int rb = bn*128 + rr + srow;
            gl_lds16(&Wb[(size_t)rb*KTOT + k0 + kc*32 + scol], &Bs[kc*4096 + rr*32]);
        }
        __syncthreads();
        #pragma unroll
        for (int kc = 0; kc < 2; kc++) {
            bf8 af[4], bf[4];
            #pragma unroll
            for (int t = 0; t < 4; t++) {
                af[t] = *(const bf8*)&As[kc*4096 + (wm + t*16 + l16)*32 + SWZ_RD(quad, l16)];
                bf[t] = *(const bf8*)&Bs[kc*4096 + (wn + t*16 + l16)*32 + SWZ_RD(quad, l16)];
            }
            #pragma unroll
            for (int mt = 0; mt < 4; mt++)
                #pragma unroll
                for (int nt = 0; nt < 4; nt++)
                    acc[mt][nt] = __builtin_amdgcn_mfma_f32_16x16x32_bf16(af[mt], bf[nt], acc[mt][nt], 0, 0, 0);
        }
        __syncthreads();
    }
    #pragma unroll
    for (int mt = 0; mt < 4; mt++)
    #pragma unroll
    for (int nt = 0; nt < 4; nt++) {
        int colg = bn*128 + wn + nt*16 + l16;
        float bv = bias[colg];
        #pragma unroll
        for (int r = 0; r < 4; r++) {
            int rowg = bm*128 + wm + mt*16 + quad*4 + r;
            short h = f2b(acc[mt][nt][r] + bv);
            int bb = rowg >> 11, s = rowg & 2047;
            if (colg < 1024) {
                int hh = colg >> 6, d = colg & 63;
                qb[(((bb*NHEAD + hh)*SEQ + s) << 6) + d] = h;
            } else if (colg < 2048) {
                int c2 = colg - 1024, hh = c2 >> 6, d = c2 & 63;
                kb[(((bb*NHEAD + hh)*SEQ + s) << 6) + d] = h;
            } else {
                int c3 = colg - 2048, hh = c3 >> 6, d = c3 & 63;
                int ssw = (s & ~63) | (((s & 15) << 2) | ((s >> 4) & 3));
                vtb[((bb*NHEAD + hh)*HDIM + d)*SEQ + ssw] = h;
            }
        }
    }
}

// ============================================================================
// Kernel 2: causal flash attention (R10 structure) + NEW: s_setprio around
// the QK^T and PV MFMA clusters (T5; m191 attn +4-7% — 4 independent
// blocks/CU give the scheduler wave-role diversity to arbitrate).
// ============================================================================
__global__ __launch_bounds__(256, 4) void attn(
    const short* __restrict__ qb, const short* __restrict__ kb,
    const short* __restrict__ vtb, short* __restrict__ ctx)
{
    __shared__ __align__(16) short Ks[2*4096];      // 16KB [buf][c][key][32sh]
    __shared__ __align__(16) short Vs[2*4096];      // 16KB
    __shared__ __align__(16) short pl[4][16*64];    //  8KB
    const int tid = threadIdx.x;
    const int w = tid >> 6, lane = tid & 63;
    const int l16 = lane & 15, quad = lane >> 4;
    const int f  = blockIdx.x;                      // 0..1023
    const int bh = f & 31;
    const int j5 = (f >> 5) & 7;
    const int hq = f >> 8;                          // 0..3
    const int tq = (hq == 0) ? j5 : (hq == 1) ? (15 - j5)
                 : (hq == 2) ? (16 + j5) : (31 - j5);
    const int q0w = tq*64 + w*16;
    const int base = bh * (SEQ*HDIM);
    short* myp = pl[w];
    const float SC = 0.125f * 1.44269504f;          // 1/sqrt(64) * log2(e)

    const int lq  = lane >> 2;
    const int lsw = SWZ_SRC(lane);

    const bool isk = (w < 2);
    short* tb = isk ? Ks : Vs;
    const int sstep = isk ? 64*HDIM : 64;
    const short* sp0; const short* sp1; const short* sp2; const short* sp3;
    int dof[4];
    {
        const int wb2 = (w & 1) * 4;
        #pragma unroll
        for (int tt = 0; tt < 4; tt++) {
            int t = wb2 + tt, cc = t & 1, g = (t >> 1) & 3;
            dof[tt] = (cc*64 + g*16)*32;
            const short* s = isk ? &kb[base + (g*16 + lq)*HDIM + cc*32 + lsw]
                                 : &vtb[base + (g*16 + lq)*SEQ + cc*32 + lsw];
            if (tt == 0) sp0 = s; else if (tt == 1) sp1 = s;
            else if (tt == 2) sp2 = s; else sp3 = s;
        }
    }

    bf8 qa[2];
    #pragma unroll
    for (int kc = 0; kc < 2; kc++)
        qa[kc] = *(const bf8*)&qb[base + (q0w + l16)*HDIM + kc*32 + quad*8];

    f4 o[4] = {};
    float lacc[4] = {};
    const int rdK = l16*32 + SWZ_RD(quad, l16);

    gl_lds16(sp0, tb + dof[0]); gl_lds16(sp1, tb + dof[1]);
    gl_lds16(sp2, tb + dof[2]); gl_lds16(sp3, tb + dof[3]);
    sp0 += sstep; sp1 += sstep; sp2 += sstep; sp3 += sstep;
    __syncthreads();

    int buf = 0;
    for (int st = 0; st <= tq; st++) {
        if (st < tq) {
            short* d = tb + (buf ^ 1)*4096;
            gl_lds16(sp0, d + dof[0]); gl_lds16(sp1, d + dof[1]);
            gl_lds16(sp2, d + dof[2]); gl_lds16(sp3, d + dof[3]);
            sp0 += sstep; sp1 += sstep; sp2 += sstep; sp3 += sstep;
        }
        const int kbase = buf*4096 + rdK;
        f4 s[4] = {};
        __builtin_amdgcn_s_setprio(1);
        #pragma unroll
        for (int kf = 0; kf < 4; kf++)
            #pragma unroll
            for (int c = 0; c < 2; c++) {
                bf8 kfr = *(const bf8*)&Ks[kbase + (c*64 + kf*16)*32];
                s[kf] = __builtin_amdgcn_mfma_f32_16x16x32_bf16(qa[c], kfr, s[kf], 0, 0, 0);
            }
        __builtin_amdgcn_s_setprio(0);
        if (st == tq) {
            const int j0 = st*64;
            #pragma unroll
            for (int r = 0; r < 4; r++) {
                const int row = quad*4 + r;
                const int qi  = q0w + row;
                float e[4];
                #pragma unroll
                for (int kf = 0; kf < 4; kf++) {
                    e[kf] = __builtin_amdgcn_exp2f(s[kf][r] * SC);
                    if (j0 + kf*16 + l16 > qi) e[kf] = 0.0f;
                    lacc[r] += e[kf];
                }
                uint u01 = __builtin_amdgcn_perm(__builtin_bit_cast(uint, e[1]),
                                                 __builtin_bit_cast(uint, e[0]), 0x07060302u);
                uint u23 = __builtin_amdgcn_perm(__builtin_bit_cast(uint, e[3]),
                                                 __builtin_bit_cast(uint, e[2]), 0x07060302u);
                uint2 pk = {u01, u23};
                int c8 = ((l16 >> 1) ^ (row & 7));
                *(uint2*)&myp[row*64 + c8*8 + (l16 & 1)*4] = pk;
            }
        } else {
            #pragma unroll
            for (int r = 0; r < 4; r++) {
                const int row = quad*4 + r;
                float e[4];
                #pragma unroll
                for (int kf = 0; kf < 4; kf++) {
                    e[kf] = __builtin_amdgcn_exp2f(s[kf][r] * SC);
                    lacc[r] += e[kf];
                }
                uint u01 = __builtin_amdgcn_perm(__builtin_bit_cast(uint, e[1]),
                                                 __builtin_bit_cast(uint, e[0]), 0x07060302u);
                uint u23 = __builtin_amdgcn_perm(__builtin_bit_cast(uint, e[3]),
                                                 __builtin_bit_cast(uint, e[2]), 0x07060302u);
                uint2 pk = {u01, u23};
                int c8 = ((l16 >> 1) ^ (row & 7));
                *(uint2*)&myp[row*64 + c8*8 + (l16 & 1)*4] = pk;
            }
        }
        asm volatile("" ::: "memory");
        bf8 pa[2];
        #pragma unroll
        for (int kc = 0; kc < 2; kc++)
            pa[kc] = *(const bf8*)&myp[l16*64 + (((kc*4 + quad) ^ (l16 & 7)))*8];
        __builtin_amdgcn_s_setprio(1);
        #pragma unroll
        for (int dt = 0; dt < 4; dt++)
            #pragma unroll
            for (int c = 0; c < 2; c++) {
                bf8 vf = *(const bf8*)&Vs[kbase + (c*64 + dt*16)*32];
                o[dt] = __builtin_amdgcn_mfma_f32_16x16x32_bf16(pa[c], vf, o[dt], 0, 0, 0);
            }
        __builtin_amdgcn_s_setprio(0);
        __syncthreads();
        buf ^= 1;
    }
    #pragma unroll
    for (int r = 0; r < 4; r++) {
        float v = lacc[r];
        v += __shfl_xor(v, 1);
        v += __shfl_xor(v, 2);
        v += __shfl_xor(v, 4);
        v += __shfl_xor(v, 8);
        lacc[r] = v;
    }
    const int b = bh >> 4, h = bh & 15;
    #pragma unroll
    for (int r = 0; r < 4; r++) {
        float inv = 1.0f / lacc[r];
        int qi = q0w + quad*4 + r;
        int rowoff = (b*SEQ + qi)*EMB + h*HDIM;
        #pragma unroll
        for (int dt = 0; dt < 4; dt++)
            ctx[rowoff + dt*16 + l16] = f2b(o[dt][r] * inv);
    }
}

// ============================================================================
// Kernel 3: output projection (R12/R0-proven form). 64x64 tile, BK=64,
// 1024 blocks = 4 blocks/CU TLP. Bias in epilogue, plain stores.
// ============================================================================
__global__ __launch_bounds__(256) void gemm_out(
    const short* __restrict__ A, const short* __restrict__ Wb,
    const float* __restrict__ bias, float* __restrict__ out)
{
    __shared__ __align__(16) short As[2*64*32];   // 8KB [kc][row][32sh]
    __shared__ __align__(16) short Bs[2*64*32];   // 8KB
    const int f = blockIdx.x;                   // 0..1023
    const int xcd = f & 7, i = f >> 3;          // i: 0..127
    const int by = xcd*2 + (i & 1);             // 0..15
    const int bx = i >> 1;                      // 0..63
    const int tid  = threadIdx.x;
    const int lane = tid & 63;
    const int w    = tid >> 6;
    const int l16  = lane & 15, quad = lane >> 4;
    const int wm   = (w >> 1) * 32, wn = (w & 1) * 32;
    const int srow = (lane >> 2);
    const int scol = SWZ_SRC(lane);
    f4 acc[2][2] = {};
    for (int k0 = 0; k0 < KTOT; k0 += 64) {
        #pragma unroll
        for (int kc = 0; kc < 2; kc++) {
            int ra = bx*64 + w*16 + srow;
            gl_lds16(&A[(size_t)ra*KTOT + k0 + kc*32 + scol],  &As[kc*2048 + (w*16)*32]);
            int rb = by*64 + w*16 + srow;
            gl_lds16(&Wb[(size_t)rb*KTOT + k0 + kc*32 + scol], &Bs[kc*2048 + (w*16)*32]);
        }
        __syncthreads();
        #pragma unroll
        for (int kc = 0; kc < 2; kc++) {
            bf8 af[2], bf[2];
            #pragma unroll
            for (int t = 0; t < 2; t++) {
                af[t] = *(const bf8*)&As[kc*2048 + (wm + t*16 + l16)*32 + SWZ_RD(quad, l16)];
                bf[t] = *(const bf8*)&Bs[kc*2048 + (wn + t*16 + l16)*32 + SWZ_RD(quad, l16)];
            }
            #pragma unroll
            for (int mt = 0; mt < 2; mt++)
                #pragma unroll
                for (int nt = 0; nt < 2; nt++)
                    acc[mt][nt] = __builtin_amdgcn_mfma_f32_16x16x32_bf16(af[mt], bf[nt], acc[mt][nt], 0, 0, 0);
        }
        __syncthreads();
    }
    #pragma unroll
    for (int mt = 0; mt < 2; mt++)
    #pragma unroll
    for (int nt = 0; nt < 2; nt++) {
        int colg = by*64 + wn + nt*16 + l16;
        float bv = bias[colg];
        #pragma unroll
        for (int r = 0; r < 4; r++) {
            int rowg = bx*64 + wm + mt*16 + quad*4 + r;
            out[(size_t)rowg*EMB + colg] = acc[mt][nt][r] + bv;
        }
    }
}

extern "C" void kernel_launch(void* const* d_in, const int* in_sizes, int n_in,
                              void* d_out, int out_size, void* d_ws, size_t ws_size,
                              hipStream_t stream) {
    const float* X    = (const float*)d_in[0];   // [B,S,E] fp32
    const float* Wqkv = (const float*)d_in[1];   // [3E,E]  fp32
    const float* Bqkv = (const float*)d_in[2];   // [3E]    fp32
    const float* Wout = (const float*)d_in[3];   // [E,E]   fp32
    const float* Bout = (const float*)d_in[4];   // [E]     fp32
    float* out = (float*)d_out;                  // [B,S,E] fp32

    short* xb    = (short*)d_ws;                 // bf16 X      (8 MB)
    short* w1b   = xb  + NX;                     // bf16 Wqkv   (6 MB)
    short* w2b   = w1b + NW1;                    // bf16 Wout   (2 MB)
    short* qb    = w2b + NW2;
    short* kb    = qb  + NX;
    short* vtb   = kb  + NX;
    short* ctx   = vtb + NX;                     // total 48 MB

    cvt_all<<<NCVT/1024, 256, 0, stream>>>(X, Wqkv, Wout, xb, w1b, w2b);
    gemm_qkv<<<dim3(768), 256, 0, stream>>>(xb, w1b, Bqkv, qb, kb, vtb);
    attn<<<dim3(1024), 256, 0, stream>>>(qb, kb, vtb, ctx);
    gemm_out<<<dim3(1024), 256, 0, stream>>>(ctx, w2b, Bout, out);
}

// Round 5
// 177.369 us; speedup vs baseline: 1.1324x; 1.0158x over previous
//
#include <hip/hip_runtime.h>
#include <hip/hip_bf16.h>

// ---- problem constants ----
#define BATCH 2
#define SEQ   2048
#define EMB   1024
#define NHEAD 16
#define HDIM  64
#define MTOT  (BATCH*SEQ)     // 4096
#define KTOT  EMB             // 1024

#define NX  (MTOT*EMB)        // 4,194,304  X elems
#define NW1 (3*EMB*EMB)       // 3,145,728  Wqkv elems
#define NW2 (EMB*EMB)         // 1,048,576  Wout elems
#define NCVT (NX+NW1+NW2)

typedef short bf8 __attribute__((ext_vector_type(8)));   // 8 bf16 (4 VGPRs) MFMA A/B frag
typedef short s4v __attribute__((ext_vector_type(4)));   // 4 bf16, 8B
typedef float f4  __attribute__((ext_vector_type(4)));   // MFMA C/D frag
typedef unsigned int uint;

__device__ __forceinline__ short f2b(float f) {
    __hip_bfloat16 h = __float2bfloat16(f);
    return __builtin_bit_cast(short, h);
}
// async global->LDS, 16B per lane; lds dest = wave-uniform base + lane*16
__device__ __forceinline__ void gl_lds16(const short* g, short* l) {
    __builtin_amdgcn_global_load_lds(
        (const __attribute__((address_space(1))) uint*)g,
        (__attribute__((address_space(3))) uint*)l, 16, 0, 0);
}
// 64B-row LDS tiles: bank swizzle (store global chunk c^f(r) at LDS chunk c).
#define SWZ_SRC(lane)      ((((lane) ^ ((lane)>>2) ^ ((lane)>>4)) & 3) * 8)
#define SWZ_RD(quad, l16)  ((((quad) ^ (l16) ^ ((l16)>>2)) & 3) * 8)

// ============================================================================
// Kernel 0: fp32 -> bf16 convert (X, Wqkv, Wout). Coalesced float4 -> bf16x4.
// ============================================================================
__global__ __launch_bounds__(256) void cvt_all(
    const float* __restrict__ X, const float* __restrict__ W1,
    const float* __restrict__ W2,
    short* __restrict__ xb, short* __restrict__ w1b, short* __restrict__ w2b)
{
    int i4 = (blockIdx.x * 256 + threadIdx.x) * 4;
    const float* src; short* dst; int off;
    if (i4 < NX)            { src = X;  dst = xb;  off = i4; }
    else if (i4 < NX + NW1) { src = W1; dst = w1b; off = i4 - NX; }
    else                    { src = W2; dst = w2b; off = i4 - NX - NW1; }
    float4 v = *(const float4*)&src[off];
    s4v o; o[0]=f2b(v.x); o[1]=f2b(v.y); o[2]=f2b(v.z); o[3]=f2b(v.w);
    *(s4v*)&dst[off] = o;
}

// ============================================================================
// Kernel 1: QKV projection — R16 == R15 (KEPT, -9.2 µs vs R0): R10-exact
// structure (128x128 tile, BK=64, single-buffer DMA staging, 768 blocks
// ~3/CU TLP) + XCD-chunked 2-D region swizzle. Measured: dur 54.3->45.1,
// MfmaUtil 17.3->21.4. NOTE: FETCH stayed 28.8MB (all 96 blocks/XCD are
// co-resident, so the 7MB instantaneous working set defeats traffic
// phasing) — the win is same-XCD L2 hit latency shortening the per-iter
// vmcnt(0) drain, not HBM traffic.
// ============================================================================
__global__ __launch_bounds__(256) void gemm_qkv(
    const short* __restrict__ Xb, const short* __restrict__ Wb,
    const float* __restrict__ bias,
    short* __restrict__ qb, short* __restrict__ kb, short* __restrict__ vtb)
{
    __shared__ __align__(16) short As[2*128*32];   // 16KB [kc][row][32sh]
    __shared__ __align__(16) short Bs[2*128*32];   // 16KB
    const int tid  = threadIdx.x;
    const int lane = tid & 63;
    const int w    = tid >> 6;
    const int l16  = lane & 15, quad = lane >> 4;
    const int wm   = (w >> 1) * 64, wn = (w & 1) * 64;
    const int srow = (lane >> 2);
    const int scol = SWZ_SRC(lane);

    // XCD-chunked region swizzle: id -> (xcd, region, pos) -> (bm, bn).
    // Bijective over 768: R = rg*8+xcd in [0,64); bm=(R&7)*4+(p&3) in [0,32);
    // bn=(R>>3)*3+(p>>2) in [0,24).
    const int id  = blockIdx.x;
    const int xcd = id & 7, k = id >> 3;            // k: 0..95
    const int rg  = k / 12, p = k - rg*12;          // rg: 0..7, p: 0..11
    const int R   = rg*8 + xcd;                     // 0..63
    const int bm  = (R & 7)*4 + (p & 3);            // 0..31  (M tile)
    const int bn  = (R >> 3)*3 + (p >> 2);          // 0..23  (N tile)

    f4 acc[4][4] = {};
    for (int k0 = 0; k0 < KTOT; k0 += 64) {
        #pragma unroll
        for (int t = 0; t < 4; t++) {
            const int rr = w*32 + (t & 1)*16;
            const int kc = t >> 1;
            int ra = bm*128 + rr + srow;
            gl_lds16(&Xb[(size_t)ra*KTOT + k0 + kc*32 + scol], &As[kc*4096 + rr*32]);
            int rb = bn*128 + rr + srow;
            gl_lds16(&Wb[(size_t)rb*KTOT + k0 + kc*32 + scol], &Bs[kc*4096 + rr*32]);
        }
        __syncthreads();
        #pragma unroll
        for (int kc = 0; kc < 2; kc++) {
            bf8 af[4], bf[4];
            #pragma unroll
            for (int t = 0; t < 4; t++) {
                af[t] = *(const bf8*)&As[kc*4096 + (wm + t*16 + l16)*32 + SWZ_RD(quad, l16)];
                bf[t] = *(const bf8*)&Bs[kc*4096 + (wn + t*16 + l16)*32 + SWZ_RD(quad, l16)];
            }
            #pragma unroll
            for (int mt = 0; mt < 4; mt++)
                #pragma unroll
                for (int nt = 0; nt < 4; nt++)
                    acc[mt][nt] = __builtin_amdgcn_mfma_f32_16x16x32_bf16(af[mt], bf[nt], acc[mt][nt], 0, 0, 0);
        }
        __syncthreads();
    }
    #pragma unroll
    for (int mt = 0; mt < 4; mt++)
    #pragma unroll
    for (int nt = 0; nt < 4; nt++) {
        int colg = bn*128 + wn + nt*16 + l16;
        float bv = bias[colg];
        #pragma unroll
        for (int r = 0; r < 4; r++) {
            int rowg = bm*128 + wm + mt*16 + quad*4 + r;
            short h = f2b(acc[mt][nt][r] + bv);
            int bb = rowg >> 11, s = rowg & 2047;
            if (colg < 1024) {
                int hh = colg >> 6, d = colg & 63;
                qb[(((bb*NHEAD + hh)*SEQ + s) << 6) + d] = h;
            } else if (colg < 2048) {
                int c2 = colg - 1024, hh = c2 >> 6, d = c2 & 63;
                kb[(((bb*NHEAD + hh)*SEQ + s) << 6) + d] = h;
            } else {
                int c3 = colg - 2048, hh = c3 >> 6, d = c3 & 63;
                int ssw = (s & ~63) | (((s & 15) << 2) | ((s >> 4) & 3));
                vtb[((bb*NHEAD + hh)*HDIM + d)*SEQ + ssw] = h;
            }
        }
    }
}

// ============================================================================
// Kernel 2: causal flash attention — R10-EXACT (R15's setprio REVERTED:
// +12 µs regression; lockstep barrier-synced waves -> setprio only delayed
// the staging waves' gl_lds issue, lengthening the per-iter critical path).
// ============================================================================
__global__ __launch_bounds__(256, 4) void attn(
    const short* __restrict__ qb, const short* __restrict__ kb,
    const short* __restrict__ vtb, short* __restrict__ ctx)
{
    __shared__ __align__(16) short Ks[2*4096];      // 16KB [buf][c][key][32sh]
    __shared__ __align__(16) short Vs[2*4096];      // 16KB
    __shared__ __align__(16) short pl[4][16*64];    //  8KB
    const int tid = threadIdx.x;
    const int w = tid >> 6, lane = tid & 63;
    const int l16 = lane & 15, quad = lane >> 4;
    const int f  = blockIdx.x;                      // 0..1023
    const int bh = f & 31;
    const int j5 = (f >> 5) & 7;
    const int hq = f >> 8;                          // 0..3
    const int tq = (hq == 0) ? j5 : (hq == 1) ? (15 - j5)
                 : (hq == 2) ? (16 + j5) : (31 - j5);
    const int q0w = tq*64 + w*16;
    const int base = bh * (SEQ*HDIM);
    short* myp = pl[w];
    const float SC = 0.125f * 1.44269504f;          // 1/sqrt(64) * log2(e)

    const int lq  = lane >> 2;
    const int lsw = SWZ_SRC(lane);

    const bool isk = (w < 2);
    short* tb = isk ? Ks : Vs;
    const int sstep = isk ? 64*HDIM : 64;
    const short* sp0; const short* sp1; const short* sp2; const short* sp3;
    int dof[4];
    {
        const int wb2 = (w & 1) * 4;
        #pragma unroll
        for (int tt = 0; tt < 4; tt++) {
            int t = wb2 + tt, cc = t & 1, g = (t >> 1) & 3;
            dof[tt] = (cc*64 + g*16)*32;
            const short* s = isk ? &kb[base + (g*16 + lq)*HDIM + cc*32 + lsw]
                                 : &vtb[base + (g*16 + lq)*SEQ + cc*32 + lsw];
            if (tt == 0) sp0 = s; else if (tt == 1) sp1 = s;
            else if (tt == 2) sp2 = s; else sp3 = s;
        }
    }

    bf8 qa[2];
    #pragma unroll
    for (int kc = 0; kc < 2; kc++)
        qa[kc] = *(const bf8*)&qb[base + (q0w + l16)*HDIM + kc*32 + quad*8];

    f4 o[4] = {};
    float lacc[4] = {};
    const int rdK = l16*32 + SWZ_RD(quad, l16);

    gl_lds16(sp0, tb + dof[0]); gl_lds16(sp1, tb + dof[1]);
    gl_lds16(sp2, tb + dof[2]); gl_lds16(sp3, tb + dof[3]);
    sp0 += sstep; sp1 += sstep; sp2 += sstep; sp3 += sstep;
    __syncthreads();

    int buf = 0;
    for (int st = 0; st <= tq; st++) {
        if (st < tq) {
            short* d = tb + (buf ^ 1)*4096;
            gl_lds16(sp0, d + dof[0]); gl_lds16(sp1, d + dof[1]);
            gl_lds16(sp2, d + dof[2]); gl_lds16(sp3, d + dof[3]);
            sp0 += sstep; sp1 += sstep; sp2 += sstep; sp3 += sstep;
        }
        const int kbase = buf*4096 + rdK;
        f4 s[4] = {};
        #pragma unroll
        for (int kf = 0; kf < 4; kf++)
            #pragma unroll
            for (int c = 0; c < 2; c++) {
                bf8 kfr = *(const bf8*)&Ks[kbase + (c*64 + kf*16)*32];
                s[kf] = __builtin_amdgcn_mfma_f32_16x16x32_bf16(qa[c], kfr, s[kf], 0, 0, 0);
            }
        if (st == tq) {
            const int j0 = st*64;
            #pragma unroll
            for (int r = 0; r < 4; r++) {
                const int row = quad*4 + r;
                const int qi  = q0w + row;
                float e[4];
                #pragma unroll
                for (int kf = 0; kf < 4; kf++) {
                    e[kf] = __builtin_amdgcn_exp2f(s[kf][r] * SC);
                    if (j0 + kf*16 + l16 > qi) e[kf] = 0.0f;
                    lacc[r] += e[kf];
                }
                uint u01 = __builtin_amdgcn_perm(__builtin_bit_cast(uint, e[1]),
                                                 __builtin_bit_cast(uint, e[0]), 0x07060302u);
                uint u23 = __builtin_amdgcn_perm(__builtin_bit_cast(uint, e[3]),
                                                 __builtin_bit_cast(uint, e[2]), 0x07060302u);
                uint2 pk = {u01, u23};
                int c8 = ((l16 >> 1) ^ (row & 7));
                *(uint2*)&myp[row*64 + c8*8 + (l16 & 1)*4] = pk;
            }
        } else {
            #pragma unroll
            for (int r = 0; r < 4; r++) {
                const int row = quad*4 + r;
                float e[4];
                #pragma unroll
                for (int kf = 0; kf < 4; kf++) {
                    e[kf] = __builtin_amdgcn_exp2f(s[kf][r] * SC);
                    lacc[r] += e[kf];
                }
                uint u01 = __builtin_amdgcn_perm(__builtin_bit_cast(uint, e[1]),
                                                 __builtin_bit_cast(uint, e[0]), 0x07060302u);
                uint u23 = __builtin_amdgcn_perm(__builtin_bit_cast(uint, e[3]),
                                                 __builtin_bit_cast(uint, e[2]), 0x07060302u);
                uint2 pk = {u01, u23};
                int c8 = ((l16 >> 1) ^ (row & 7));
                *(uint2*)&myp[row*64 + c8*8 + (l16 & 1)*4] = pk;
            }
        }
        asm volatile("" ::: "memory");
        bf8 pa[2];
        #pragma unroll
        for (int kc = 0; kc < 2; kc++)
            pa[kc] = *(const bf8*)&myp[l16*64 + (((kc*4 + quad) ^ (l16 & 7)))*8];
        #pragma unroll
        for (int dt = 0; dt < 4; dt++)
            #pragma unroll
            for (int c = 0; c < 2; c++) {
                bf8 vf = *(const bf8*)&Vs[kbase + (c*64 + dt*16)*32];
                o[dt] = __builtin_amdgcn_mfma_f32_16x16x32_bf16(pa[c], vf, o[dt], 0, 0, 0);
            }
        __syncthreads();
        buf ^= 1;
    }
    #pragma unroll
    for (int r = 0; r < 4; r++) {
        float v = lacc[r];
        v += __shfl_xor(v, 1);
        v += __shfl_xor(v, 2);
        v += __shfl_xor(v, 4);
        v += __shfl_xor(v, 8);
        lacc[r] = v;
    }
    const int b = bh >> 4, h = bh & 15;
    #pragma unroll
    for (int r = 0; r < 4; r++) {
        float inv = 1.0f / lacc[r];
        int qi = q0w + quad*4 + r;
        int rowoff = (b*SEQ + qi)*EMB + h*HDIM;
        #pragma unroll
        for (int dt = 0; dt < 4; dt++)
            ctx[rowoff + dt*16 + l16] = f2b(o[dt][r] * inv);
    }
}

// ============================================================================
// Kernel 3: output projection (R12/R0-proven form). 64x64 tile, BK=64,
// 1024 blocks = 4 blocks/CU TLP. Bias in epilogue, plain stores.
// ============================================================================
__global__ __launch_bounds__(256) void gemm_out(
    const short* __restrict__ A, const short* __restrict__ Wb,
    const float* __restrict__ bias, float* __restrict__ out)
{
    __shared__ __align__(16) short As[2*64*32];   // 8KB [kc][row][32sh]
    __shared__ __align__(16) short Bs[2*64*32];   // 8KB
    const int f = blockIdx.x;                   // 0..1023
    const int xcd = f & 7, i = f >> 3;          // i: 0..127
    const int by = xcd*2 + (i & 1);             // 0..15
    const int bx = i >> 1;                      // 0..63
    const int tid  = threadIdx.x;
    const int lane = tid & 63;
    const int w    = tid >> 6;
    const int l16  = lane & 15, quad = lane >> 4;
    const int wm   = (w >> 1) * 32, wn = (w & 1) * 32;
    const int srow = (lane >> 2);
    const int scol = SWZ_SRC(lane);
    f4 acc[2][2] = {};
    for (int k0 = 0; k0 < KTOT; k0 += 64) {
        #pragma unroll
        for (int kc = 0; kc < 2; kc++) {
            int ra = bx*64 + w*16 + srow;
            gl_lds16(&A[(size_t)ra*KTOT + k0 + kc*32 + scol],  &As[kc*2048 + (w*16)*32]);
            int rb = by*64 + w*16 + srow;
            gl_lds16(&Wb[(size_t)rb*KTOT + k0 + kc*32 + scol], &Bs[kc*2048 + (w*16)*32]);
        }
        __syncthreads();
        #pragma unroll
        for (int kc = 0; kc < 2; kc++) {
            bf8 af[2], bf[2];
            #pragma unroll
            for (int t = 0; t < 2; t++) {
                af[t] = *(const bf8*)&As[kc*2048 + (wm + t*16 + l16)*32 + SWZ_RD(quad, l16)];
                bf[t] = *(const bf8*)&Bs[kc*2048 + (wn + t*16 + l16)*32 + SWZ_RD(quad, l16)];
            }
            #pragma unroll
            for (int mt = 0; mt < 2; mt++)
                #pragma unroll
                for (int nt = 0; nt < 2; nt++)
                    acc[mt][nt] = __builtin_amdgcn_mfma_f32_16x16x32_bf16(af[mt], bf[nt], acc[mt][nt], 0, 0, 0);
        }
        __syncthreads();
    }
    #pragma unroll
    for (int mt = 0; mt < 2; mt++)
    #pragma unroll
    for (int nt = 0; nt < 2; nt++) {
        int colg = by*64 + wn + nt*16 + l16;
        float bv = bias[colg];
        #pragma unroll
        for (int r = 0; r < 4; r++) {
            int rowg = bx*64 + wm + mt*16 + quad*4 + r;
            out[(size_t)rowg*EMB + colg] = acc[mt][nt][r] + bv;
        }
    }
}

extern "C" void kernel_launch(void* const* d_in, const int* in_sizes, int n_in,
                              void* d_out, int out_size, void* d_ws, size_t ws_size,
                              hipStream_t stream) {
    const float* X    = (const float*)d_in[0];   // [B,S,E] fp32
    const float* Wqkv = (const float*)d_in[1];   // [3E,E]  fp32
    const float* Bqkv = (const float*)d_in[2];   // [3E]    fp32
    const float* Wout = (const float*)d_in[3];   // [E,E]   fp32
    const float* Bout = (const float*)d_in[4];   // [E]     fp32
    float* out = (float*)d_out;                  // [B,S,E] fp32

    short* xb    = (short*)d_ws;                 // bf16 X      (8 MB)
    short* w1b   = xb  + NX;                     // bf16 Wqkv   (6 MB)
    short* w2b   = w1b + NW1;                    // bf16 Wout   (2 MB)
    short* qb    = w2b + NW2;
    short* kb    = qb  + NX;
    short* vtb   = kb  + NX;
    short* ctx   = vtb + NX;                     // total 48 MB

    cvt_all<<<NCVT/1024, 256, 0, stream>>>(X, Wqkv, Wout, xb, w1b, w2b);
    gemm_qkv<<<dim3(768), 256, 0, stream>>>(xb, w1b, Bqkv, qb, kb, vtb);
    attn<<<dim3(1024), 256, 0, stream>>>(qb, kb, vtb, ctx);
    gemm_out<<<dim3(1024), 256, 0, stream>>>(ctx, w2b, Bout, out);
}